// Round 6
// baseline (255.046 us; speedup 1.0000x reference)
//
#include <hip/hip_runtime.h>
#include <stdint.h>

typedef float f32x4 __attribute__((ext_vector_type(4)));
typedef __bf16 bf16x8 __attribute__((ext_vector_type(8)));
typedef unsigned short ushortx8 __attribute__((ext_vector_type(8)));

#define D_DIM 512
#define KGC 10
#define NCLU 8
#define BATCH 32
#define WPOS 250
#define WPAD 256
#define KDIM 3584   // 512*7
#define MROWS 522   // 512 feat + 10 assign
#define MPAD 528    // Y rows per batch
#define MBIG 640    // padded W rows (4 x 160)
#define BM 160      // block m-tile (4 m-slices)
#define BN 128      // block n-tile
#define NS 56       // K steps (KDIM/64), full K per block
#define NT 64       // n-tiles of 128 (N = 8192)
#define KSG 56
// XS: bf16 X pre-arranged in MFMA B-fragment lane order.
// unit u = ks*512 + nf*64 + lane (16B each): holds
// X[n = nt*128 + nf*16 + (lane&15)][k = ksg*64 + ks*32 + (lane>>4)*8 + e], e=0..7
#define XTILE 8192  // ushorts per (nt,ksg) tile

__device__ __forceinline__ float bf2f(unsigned short u) {
  union { unsigned int i; float f; } v; v.i = ((unsigned int)u) << 16; return v.f;
}
__device__ __forceinline__ unsigned short f2bf(float f) {
  union { float f; unsigned int i; } v; v.f = f;
  unsigned int r = v.i + 0x7FFFu + ((v.i >> 16) & 1u);
  return (unsigned short)(r >> 16);
}

__device__ __forceinline__ void load_lds16(const void* g, void* l) {
  __builtin_amdgcn_global_load_lds(
      (const __attribute__((address_space(1))) void*)g,
      (__attribute__((address_space(3))) void*)l, 16, 0, 0);
}

// ---------------- prep2: W-rows (bf16 concat) + bias + X fragment-order converter ----------------
// blocks 0..639: Wcat row r; blocks 640..4223: XS tile (nt, ksg)
__global__ __launch_bounds__(256) void prep2_kernel(
    const float* __restrict__ fw, const float* __restrict__ fb,
    const float* __restrict__ aw, const float* __restrict__ ab,
    const float* __restrict__ x,
    unsigned short* __restrict__ Wcat, float* __restrict__ bcat,
    unsigned short* __restrict__ XS) {
  const int bid = blockIdx.x;
  const int tid = threadIdx.x;
  if (bid < MBIG) {
    int r = bid;
    unsigned short* dst = Wcat + (size_t)r * KDIM;
    const float* src = (r < D_DIM) ? (fw + (size_t)r * KDIM)
                     : (r < MROWS) ? (aw + (size_t)(r - D_DIM) * KDIM)
                                   : nullptr;
    for (int i = tid; i < KDIM / 4; i += 256) {
      unsigned short o0 = 0, o1 = 0, o2 = 0, o3 = 0;
      if (src) {
        float4 v = ((const float4*)src)[i];
        o0 = f2bf(v.x); o1 = f2bf(v.y); o2 = f2bf(v.z); o3 = f2bf(v.w);
      }
      ushort4 o; o.x = o0; o.y = o1; o.z = o2; o.w = o3;
      ((ushort4*)dst)[i] = o;
    }
    if (tid == 0)
      bcat[r] = r < D_DIM ? fb[r] : (r < MROWS ? ab[r - D_DIM] : 0.f);
  } else {
    const int xt = bid - MBIG;
    const int nt = xt / KSG, ksg = xt - nt * KSG;
    unsigned short* tb = XS + (size_t)(nt * KSG + ksg) * XTILE;
#pragma unroll
    for (int i = 0; i < 4; i++) {
      const int L = tid + 256 * i;
      const int ks = L >> 9, nf = (L >> 6) & 7, lane = L & 63;
      const int fr = lane & 15, kg = lane >> 4;
      const int n = nt * 128 + nf * 16 + fr;
      const int b = n >> 8, col = n & 255;
      const int k0 = ksg * 64 + ks * 32 + kg * 8;
      const float* xp = x + ((size_t)b * KDIM + k0) * WPOS + col;
      ushortx8 pk;
      if (col < WPOS) {
#pragma unroll
        for (int e = 0; e < 8; e++) pk[e] = f2bf(xp[(size_t)e * WPOS]);
      } else {
#pragma unroll
        for (int e = 0; e < 8; e++) pk[e] = 0;
      }
      *(ushortx8*)&tb[(size_t)L * 8] = pk;
    }
  }
}

// ---------------- fused full-K GEMM: Y[b][m][w](bf16) = relu_if_feat(W @ x + bias) ----------------
// 512 thr (8 waves 2m x 4n, wave 80x32), grid (64 nt, 4 mh) = 256 blocks = 1/CU.
// Deep pipeline: 4 LDS W-buffers + 4 X-register sets, staging issued 2 STEPS AHEAD,
// raw s_barrier with COUNTED vmcnt(7) (3 dma + 4 X-loads per wave per batch, uniform),
// never vmcnt(0) until the final step. No P partials: bias+ReLU+bf16 epilogue fused.
__global__ __launch_bounds__(512, 2) void gemm_fused(
    const unsigned short* __restrict__ XS, const unsigned short* __restrict__ Wcat,
    const float* __restrict__ bcat, unsigned short* __restrict__ Y) {
  __shared__ __align__(16) unsigned short Wl[4][BM * 64];  // 4 x 20,480 B swizzled
  const int tid = threadIdx.x;
  const int nt = blockIdx.x, mh = blockIdx.y;
  // ids = nt + 64*mh: the 4 mh-sharers of an XS slice differ by 64 -> same XCD.
  const int lane = tid & 63, wv = tid >> 6;     // 8 waves
  const int wm = wv >> 2, wn = wv & 3;          // 2m x 4n -> wave 80x32
  const int fr = lane & 15, kg = lane >> 4;
  const int sx = fr & 7;
  const unsigned short* Wg = Wcat + (size_t)mh * BM * KDIM;
  const unsigned short* xsb = XS + (size_t)nt * (KSG * XTILE) + (wn * 1024 + lane * 8);

  // W lds-dma: 160 rows x 8 octets = 1280 slots. it=0,1: slots tid, 512+tid;
  // it=2: slots 1024+(tid&255) duplicated (same data) -> EXACTLY 3 dma per thread
  // -> wave-uniform vmcnt accounting. LDS dest linear; global source pre-swizzled.
  auto stageW = [&](int st, int buf) {
#pragma unroll
    for (int it = 0; it < 3; it++) {
      int s = (it < 2) ? it * 512 + tid : 1024 + (tid & 255);
      int row = s >> 3, p = s & 7;
      int blk = p ^ (row & 7);
      load_lds16(Wg + (size_t)row * KDIM + st * 64 + blk * 8, &Wl[buf][s * 8]);
    }
  };
  auto loadX = [&](int st, bf16x8& x0, bf16x8& x1, bf16x8& x2, bf16x8& x3) {
    const unsigned short* p = xsb + (size_t)st * XTILE;
    x0 = *(const bf16x8*)(p);               // ks0, nf=2wn
    x1 = *(const bf16x8*)(p + 512);         // ks0, nf=2wn+1
    x2 = *(const bf16x8*)(p + 4096);        // ks1, nf=2wn
    x3 = *(const bf16x8*)(p + 4096 + 512);  // ks1, nf=2wn+1
  };

  f32x4 acc[5][2];
  const f32x4 zero = {0.f, 0.f, 0.f, 0.f};
#pragma unroll
  for (int f = 0; f < 5; f++) { acc[f][0] = zero; acc[f][1] = zero; }

  auto compute = [&](const unsigned short* wb, bf16x8 b00, bf16x8 b01,
                     bf16x8 b10, bf16x8 b11) {
#pragma unroll
    for (int ks = 0; ks < 2; ks++) {
      bf16x8 b0 = ks ? b10 : b00;
      bf16x8 b1 = ks ? b11 : b01;
      const int off = ((ks * 4 + kg) ^ sx) * 8;
#pragma unroll
      for (int f = 0; f < 5; f++) {
        bf16x8 af = *(const bf16x8*)&wb[(wm * 80 + f * 16 + fr) * 64 + off];
        acc[f][0] = __builtin_amdgcn_mfma_f32_16x16x32_bf16(af, b0, acc[f][0], 0, 0, 0);
        acc[f][1] = __builtin_amdgcn_mfma_f32_16x16x32_bf16(af, b1, acc[f][1], 0, 0, 0);
      }
    }
  };

  bf16x8 xA0, xA1, xA2, xA3, xB0, xB1, xB2, xB3;
  bf16x8 xC0, xC1, xC2, xC3, xD0, xD1, xD2, xD3;

  // prologue: issue batches 0 and 1 (7 VM ops each)
  stageW(0, 0); loadX(0, xA0, xA1, xA2, xA3);
  stageW(1, 1); loadX(1, xB0, xB1, xB2, xB3);

  // Per step u: wait batch u (vmcnt(7): only batch u+1 younger), barrier (all waves'
  // dma for buf u landed), issue batch u+2 (overwrites buf (u+2)&3, last read at
  // step u-2 -- two barriers ago, safe), compute(u). sched_barrier(0) pins ds_reads
  // below the barrier (cross-wave dma visibility; rule #18).
#define STEP(u, BUF, PBUF, CX0, CX1, CX2, CX3, PX0, PX1, PX2, PX3)           \
  {                                                                          \
    if ((u) + 1 < NS) { asm volatile("s_waitcnt vmcnt(7)" ::: "memory"); }   \
    else              { asm volatile("s_waitcnt vmcnt(0)" ::: "memory"); }   \
    __builtin_amdgcn_s_barrier();                                            \
    __builtin_amdgcn_sched_barrier(0);                                       \
    if ((u) + 2 < NS) {                                                      \
      stageW((u) + 2, PBUF);                                                 \
      loadX((u) + 2, PX0, PX1, PX2, PX3);                                    \
    }                                                                        \
    compute(Wl[BUF], CX0, CX1, CX2, CX3);                                    \
  }

  for (int t = 0; t < NS; t += 4) {
    STEP(t + 0, 0, 2, xA0, xA1, xA2, xA3, xC0, xC1, xC2, xC3);
    STEP(t + 1, 1, 3, xB0, xB1, xB2, xB3, xD0, xD1, xD2, xD3);
    STEP(t + 2, 2, 0, xC0, xC1, xC2, xC3, xA0, xA1, xA2, xA3);
    STEP(t + 3, 3, 1, xD0, xD1, xD2, xD3, xB0, xB1, xB2, xB3);
  }
#undef STEP

  // fused epilogue: C/D frag col = lane&15 (n), row = kg*4 + r (m within frag)
  const int bb = (nt * BN) >> 8;            // all 128 block cols in same batch
  const int cbase = (nt * BN) & 255;
  unsigned short* Yb = Y + (size_t)bb * MPAD * WPAD;
#pragma unroll
  for (int f = 0; f < 5; f++) {
    const int m0 = mh * BM + wm * 80 + f * 16 + kg * 4;
#pragma unroll
    for (int nf = 0; nf < 2; nf++) {
      const int c = cbase + wn * 32 + nf * 16 + fr;
#pragma unroll
      for (int r = 0; r < 4; r++) {
        const int m = m0 + r;
        if (m < MPAD) {
          float v = acc[f][nf][r] + bcat[m];
          if (m < D_DIM) v = fmaxf(v, 0.f);
          Yb[(size_t)m * WPAD + c] = f2bf(v);
        }
      }
    }
  }
}

// ---------------- epilogue: softmax, agg, subtract centroids*s_sum, L2-normalize ----------------
// 512 thr (8 waves, 1 d-row per thread), float4 broadcast soft reads,
// 8 independent accumulators to break the fma dependency chain.
__global__ __launch_bounds__(512) void epi_kernel(
    const unsigned short* __restrict__ Y, const float* __restrict__ cent,
    float* __restrict__ out) {
  __shared__ float soft[WPAD];
  __shared__ float red[8];
  const int b = blockIdx.x >> 3, k = blockIdx.x & 7;
  const int tid = threadIdx.x;
  const unsigned short* Yb = Y + (size_t)b * MPAD * WPAD;

  float sv = 0.f;
  if (tid < WPOS) {
    float lg[KGC];
    float mx = -1e30f;
#pragma unroll
    for (int j = 0; j < KGC; j++) {
      lg[j] = bf2f(Yb[(size_t)(D_DIM + j) * WPAD + tid]);
      mx = fmaxf(mx, lg[j]);
    }
    float s = 0.f, ek = 0.f;
#pragma unroll
    for (int j = 0; j < KGC; j++) {
      float e = __expf(lg[j] - mx);
      s += e;
      if (j == k) ek = e;
    }
    sv = ek / s;
  }
  if (tid < WPAD) soft[tid] = sv;   // tids 250..255 write 0
  __syncthreads();

  float v = sv;
#pragma unroll
  for (int o = 32; o > 0; o >>= 1) v += __shfl_down(v, o, 64);
  if ((tid & 63) == 0) red[tid >> 6] = v;
  __syncthreads();
  float ssum = 0.f;
#pragma unroll
  for (int i = 0; i < 8; i++) ssum += red[i];

  float a[8];
#pragma unroll
  for (int u = 0; u < 8; u++) a[u] = 0.f;
  const unsigned short* row = Yb + (size_t)tid * WPAD;
  for (int w = 0; w < WPAD; w += 8) {
    ushortx8 f0 = *(const ushortx8*)(row + w);
    float4 s0 = *(const float4*)&soft[w];
    float4 s1 = *(const float4*)&soft[w + 4];
    a[0] += bf2f(f0[0]) * s0.x;
    a[1] += bf2f(f0[1]) * s0.y;
    a[2] += bf2f(f0[2]) * s0.z;
    a[3] += bf2f(f0[3]) * s0.w;
    a[4] += bf2f(f0[4]) * s1.x;
    a[5] += bf2f(f0[5]) * s1.y;
    a[6] += bf2f(f0[6]) * s1.z;
    a[7] += bf2f(f0[7]) * s1.w;
  }
  float asum = ((a[0] + a[1]) + (a[2] + a[3])) + ((a[4] + a[5]) + (a[6] + a[7]));
  float c = asum - cent[(size_t)tid * KGC + k] * ssum;

  __syncthreads();
  float q = c * c;
#pragma unroll
  for (int o = 32; o > 0; o >>= 1) q += __shfl_down(q, o, 64);
  if ((tid & 63) == 0) red[tid >> 6] = q;
  __syncthreads();
  float nsum = 0.f;
#pragma unroll
  for (int i = 0; i < 8; i++) nsum += red[i];
  float norm = sqrtf(nsum);
  float inv = 1.f / fmaxf(norm, 1e-12f);

  float* ob = out + (size_t)b * (NCLU * D_DIM) + (size_t)k * D_DIM;
  ob[tid] = c * inv;
}

extern "C" void kernel_launch(void* const* d_in, const int* in_sizes, int n_in,
                              void* d_out, int out_size, void* d_ws, size_t ws_size,
                              hipStream_t stream) {
  const float* x  = (const float*)d_in[0];
  const float* fw = (const float*)d_in[1];
  const float* fb = (const float*)d_in[2];
  const float* aw = (const float*)d_in[3];
  const float* ab = (const float*)d_in[4];
  const float* ce = (const float*)d_in[5];
  float* out = (float*)d_out;
  char* ws = (char*)d_ws;

  const size_t WC_BYTES = (size_t)MBIG * KDIM * 2;        //  4,587,520
  const size_t BC_BYTES = 4096;
  const size_t XS_BYTES = (size_t)NT * KSG * XTILE * 2;   // 58,720,256
  unsigned short* Wc = (unsigned short*)(ws);
  float*          bc = (float*)(ws + WC_BYTES);
  unsigned short* XSp= (unsigned short*)(ws + WC_BYTES + BC_BYTES);
  // Y is SEPARATE from XS (gemm reads XS while writing Y -- no aliasing).
  unsigned short* Yv = (unsigned short*)(ws + WC_BYTES + BC_BYTES + XS_BYTES);
  // total ws use ~72 MiB (Y = 32*528*256*2 = 8,650,752)

  prep2_kernel<<<MBIG + NT * KSG, 256, 0, stream>>>(fw, fb, aw, ab, x, Wc, bc, XSp);
  gemm_fused<<<dim3(NT, 4), 512, 0, stream>>>(XSp, Wc, bc, Yv);
  epi_kernel<<<BATCH * NCLU, 512, 0, stream>>>(Yv, ce, out);
}